// Round 2
// baseline (125.819 us; speedup 1.0000x reference)
//
#include <hip/hip_runtime.h>
#include <hip/hip_fp16.h>
#include <cstdint>

constexpr int GN   = 41;                // grid points per dim
constexpr int VOX  = GN * GN * GN;      // 68921 spatial points
constexpr int CH   = 32;                // channels
constexpr int EF   = 128;               // encoder features
constexpr int TILE = 64;                // elements per block

typedef _Float16 h2 __attribute__((ext_vector_type(2)));
typedef float    f2v __attribute__((ext_vector_type(2)));

__device__ __forceinline__ uint32_t pack_h2(float a, float b) {
    __half2 h = __floats2half2_rn(a, b);
    return __builtin_bit_cast(uint32_t, h);
}

// -------- Pass 1: grid [C][X][Y][Z] fp32 -> [X][Y][Z][C] fp16 (gT)  +  ----
// -------- enc_w fp32 -> packed f16 k-pairs (ewP[f][p], p = k/2) ------------
__global__ __launch_bounds__(256) void prep_k(
    const float* __restrict__ src, const float* __restrict__ enc_w,
    __half* __restrict__ gT, uint32_t* __restrict__ ewP) {
    int idx = blockIdx.x * 256 + threadIdx.x;
    if (idx < VOX * 4) {
        int s  = idx >> 2;
        int ck = idx & 3;
        float v[8];
#pragma unroll
        for (int i = 0; i < 8; ++i) v[i] = src[(ck * 8 + i) * VOX + s];
        *reinterpret_cast<uint4*>(gT + (size_t)s * CH + ck * 8) =
            make_uint4(pack_h2(v[0], v[1]), pack_h2(v[2], v[3]),
                       pack_h2(v[4], v[5]), pack_h2(v[6], v[7]));
    }
    int pid = idx - VOX * 4;
    if (pid >= 0 && pid < 512) {        // pid = f*4 + qq
        int f  = pid >> 2;
        int qq = pid & 3;
        const float* wr = enc_w + f * CH + qq * 8;   // 8 contiguous k
        float4 a = *reinterpret_cast<const float4*>(wr);
        float4 b = *reinterpret_cast<const float4*>(wr + 4);
        // ewP[f*16 + qq*4 + i] = halves (k=qq*8+2i, qq*8+2i+1)
        *reinterpret_cast<uint4*>(ewP + (size_t)pid * 4) =
            make_uint4(pack_h2(a.x, a.y), pack_h2(a.z, a.w),
                       pack_h2(b.x, b.y), pack_h2(b.z, b.w));
    }
}

__device__ __forceinline__ void bspline_w(float t, float w[4]) {
    float t2 = t * t, t3 = t2 * t;
    const float k = 1.0f / 6.0f;
    w[0] = k * (1.0f - 3.0f * t + 3.0f * t2 - t3);
    w[1] = k * (4.0f - 6.0f * t2 + 3.0f * t3);
    w[2] = k * (1.0f + 3.0f * t + 3.0f * t2 - 3.0f * t3);
    w[3] = k * t3;
}

// f32 fma with f16 operand promoted in-instruction (exact same numerics as
// cvt_f32_f16 + fma_f32, but one VALU op instead of two).
__device__ __forceinline__ void fma_mix_lo(float& a, float w, uint32_t p) {
    asm("v_fma_mix_f32 %0, %1, %2, %0 op_sel:[0,0,0] op_sel_hi:[0,1,0]"
        : "+v"(a) : "v"(w), "v"(p));
}
__device__ __forceinline__ void fma_mix_hi(float& a, float w, uint32_t p) {
    asm("v_fma_mix_f32 %0, %1, %2, %0 op_sel:[0,1,0] op_sel_hi:[0,1,0]"
        : "+v"(a) : "v"(w), "v"(p));
}

// -------- Pass 2 ----------------------------------------------------------
// Phase 1: lane = eq(2b)|zsl(2b)|ck(2b); uint4 = 8 fp16 channels per load;
//   v_fma_mix f32 accumulate; z-reduce shfl_xor(4,8); lig_x -> LDS as packed
//   h2 pairs. nb loads hoisted + qi loop fully unrolled so the 4 elements'
//   16-load gather windows overlap (was: unroll 1 -> serial windows).
// Phase 2: lane = feature pair, wave owns its own 16 elements (wave-private
//   LDS flow, no barrier). Weights in VGPRs; out stores NON-TEMPORAL so the
//   65 MB write stream doesn't evict gT (4.4 MB ~ L2-sized) from L2.
__global__ __launch_bounds__(256, 4) void lig_main(
    const float* __restrict__ nb, const __half* __restrict__ gT,
    const uint32_t* __restrict__ ewP, const float* __restrict__ enc_b,
    float* __restrict__ out, int batch) {

    __shared__ __align__(16) uint32_t xs[TILE * 16];   // 4 KB, h2 ch-pairs

    const int tid  = threadIdx.x;
    const int lane = tid & 63;
    const int wv   = tid >> 6;
    const int eq   = lane >> 4;         // element in quad
    const int zsl  = (lane >> 2) & 3;   // z tap
    const int ck   = (lane & 3) * 8;    // channel octet base
    const int base_e = blockIdx.x * TILE;
    (void)batch;

    // Hoist all nb loads (read-once stream -> non-temporal).
    float q0[4], q1[4], q2[4];
#pragma unroll
    for (int qi = 0; qi < 4; ++qi) {
        const int e = base_e + wv * 16 + qi * 4 + eq;
        q0[qi] = __builtin_nontemporal_load(nb + 3 * e);
        q1[qi] = __builtin_nontemporal_load(nb + 3 * e + 1);
        q2[qi] = __builtin_nontemporal_load(nb + 3 * e + 2);
    }

    // ---------------- Phase 1: interpolate 16 elements per wave ------------
#pragma unroll
    for (int qi = 0; qi < 4; ++qi) {
        const int eloc = wv * 16 + qi * 4 + eq;

        float ux = fminf(fmaxf(0.5f + 0.1f * q0[qi], 0.0f), 1.0f) * 40.0f;
        float uy = fminf(fmaxf(0.5f + 0.1f * q1[qi], 0.0f), 1.0f) * 40.0f;
        float uz = fminf(fmaxf(0.5f + 0.1f * q2[qi], 0.0f), 1.0f) * 40.0f;
        int bx = (int)ux, by = (int)uy, bz = (int)uz;
        float wx[4], wy[4], wz[4];
        bspline_w(ux - (float)bx, wx);
        bspline_w(uy - (float)by, wy);
        bspline_w(uz - (float)bz, wz);

        const float wzl = wz[zsl];      // fold z weight into x weights
#pragma unroll
        for (int o = 0; o < 4; ++o) wx[o] *= wzl;

        int X[4], Y[4];
#pragma unroll
        for (int o = 0; o < 4; ++o) {
            X[o] = min(max(bx + o - 1, 0), GN - 1) * (GN * GN * CH);
            Y[o] = min(max(by + o - 1, 0), GN - 1) * (GN * CH);
        }
        const int Zoff = min(max(bz + zsl - 1, 0), GN - 1) * CH + ck;

        float acc[8];
#pragma unroll
        for (int k = 0; k < 8; ++k) acc[k] = 0.0f;

#pragma unroll
        for (int i = 0; i < 4; ++i) {
#pragma unroll
            for (int j = 0; j < 4; ++j) {
                const uint4 raw =
                    *reinterpret_cast<const uint4*>(gT + (X[i] + Y[j] + Zoff));
                const float wt = wx[i] * wy[j];
                fma_mix_lo(acc[0], wt, raw.x);
                fma_mix_hi(acc[1], wt, raw.x);
                fma_mix_lo(acc[2], wt, raw.y);
                fma_mix_hi(acc[3], wt, raw.y);
                fma_mix_lo(acc[4], wt, raw.z);
                fma_mix_hi(acc[5], wt, raw.z);
                fma_mix_lo(acc[6], wt, raw.w);
                fma_mix_hi(acc[7], wt, raw.w);
            }
        }

#pragma unroll
        for (int k = 0; k < 8; ++k) {
            acc[k] += __shfl_xor(acc[k], 4);
            acc[k] += __shfl_xor(acc[k], 8);
        }

        if ((lane & 12) == 0) {         // zsl==0 lanes hold the z-sums
            uint32_t d0 = __builtin_bit_cast(
                uint32_t, __builtin_amdgcn_cvt_pkrtz(acc[0], acc[1]));
            uint32_t d1 = __builtin_bit_cast(
                uint32_t, __builtin_amdgcn_cvt_pkrtz(acc[2], acc[3]));
            uint32_t d2 = __builtin_bit_cast(
                uint32_t, __builtin_amdgcn_cvt_pkrtz(acc[4], acc[5]));
            uint32_t d3 = __builtin_bit_cast(
                uint32_t, __builtin_amdgcn_cvt_pkrtz(acc[6], acc[7]));
            *reinterpret_cast<uint4*>(&xs[eloc * 16 + (lane & 3) * 4]) =
                make_uint4(d0, d1, d2, d3);
        }
    }

    // ---------------- Phase 2: 32 -> 128 matmul, coalesced nt stores -------
    const int f0 = lane * 2;
    uint32_t w0[16], w1[16];
    {
        const uint4* wp0 = reinterpret_cast<const uint4*>(ewP + (size_t)f0 * 16);
        const uint4* wp1 = reinterpret_cast<const uint4*>(ewP + (size_t)(f0 + 1) * 16);
#pragma unroll
        for (int g = 0; g < 4; ++g) {
            uint4 a = wp0[g];
            w0[4 * g + 0] = a.x; w0[4 * g + 1] = a.y;
            w0[4 * g + 2] = a.z; w0[4 * g + 3] = a.w;
            uint4 b = wp1[g];
            w1[4 * g + 0] = b.x; w1[4 * g + 1] = b.y;
            w1[4 * g + 2] = b.z; w1[4 * g + 3] = b.w;
        }
    }
    const float2 bb = *reinterpret_cast<const float2*>(enc_b + f0);

    float*          obase = out + (size_t)(base_e + wv * 16) * EF + f0;
    const uint32_t* xbase = xs + (size_t)(wv * 16) * 16;

#pragma unroll 4
    for (int i = 0; i < 16; ++i) {
        const uint32_t* xp = xbase + i * 16;
        uint4 x0 = *reinterpret_cast<const uint4*>(xp);       // broadcast
        uint4 x1 = *reinterpret_cast<const uint4*>(xp + 4);
        uint4 x2 = *reinterpret_cast<const uint4*>(xp + 8);
        uint4 x3 = *reinterpret_cast<const uint4*>(xp + 12);
        uint32_t xd[16] = {x0.x, x0.y, x0.z, x0.w, x1.x, x1.y, x1.z, x1.w,
                           x2.x, x2.y, x2.z, x2.w, x3.x, x3.y, x3.z, x3.w};
        float s0 = bb.x, s1 = bb.y;
#pragma unroll
        for (int p = 0; p < 16; ++p) {
            s0 = __builtin_amdgcn_fdot2(__builtin_bit_cast(h2, xd[p]),
                                        __builtin_bit_cast(h2, w0[p]), s0, false);
            s1 = __builtin_amdgcn_fdot2(__builtin_bit_cast(h2, xd[p]),
                                        __builtin_bit_cast(h2, w1[p]), s1, false);
        }
        f2v o; o.x = s0; o.y = s1;
        __builtin_nontemporal_store(
            o, reinterpret_cast<f2v*>(obase + (size_t)i * EF));
    }
}

extern "C" void kernel_launch(void* const* d_in, const int* in_sizes, int n_in,
                              void* d_out, int out_size, void* d_ws,
                              size_t ws_size, hipStream_t stream) {
    const float* nb   = (const float*)d_in[0];
    const float* grid = (const float*)d_in[1];
    const float* ew   = (const float*)d_in[2];
    const float* eb   = (const float*)d_in[3];
    float*       out  = (float*)d_out;
    __half*      gTh  = (__half*)d_ws;                       // 4.41 MB
    uint32_t*    ewP  = (uint32_t*)(gTh + (size_t)VOX * CH); // + 8 KB

    int batch = in_sizes[0] / 3;

    int prep_blocks = (VOX * 4 + 512 + 255) / 256;
    prep_k<<<prep_blocks, 256, 0, stream>>>(grid, ew, gTh, ewP);
    lig_main<<<batch / TILE, 256, 0, stream>>>(nb, gTh, ewP, eb, out, batch);
}

// Round 4
// 124.270 us; speedup vs baseline: 1.0125x; 1.0125x over previous
//
#include <hip/hip_runtime.h>
#include <hip/hip_fp16.h>
#include <cstdint>

constexpr int GN   = 41;                // grid points per dim
constexpr int VOX  = GN * GN * GN;      // 68921 spatial points
constexpr int CH   = 32;                // channels
constexpr int EF   = 128;               // encoder features
constexpr int TILE = 64;                // elements per block

typedef _Float16 h2 __attribute__((ext_vector_type(2)));
typedef float    f2v __attribute__((ext_vector_type(2)));

__device__ __forceinline__ uint32_t pack_h2(float a, float b) {
    __half2 h = __floats2half2_rn(a, b);
    return __builtin_bit_cast(uint32_t, h);
}

// -------- Pass 1: grid [C][X][Y][Z] fp32 -> [X][Y][Z][C] fp16 (gT)  +  ----
// -------- enc_w fp32 -> packed f16 k-pairs (ewP[f][p], p = k/2) ------------
__global__ __launch_bounds__(256) void prep_k(
    const float* __restrict__ src, const float* __restrict__ enc_w,
    __half* __restrict__ gT, uint32_t* __restrict__ ewP) {
    int idx = blockIdx.x * 256 + threadIdx.x;
    if (idx < VOX * 4) {
        int s  = idx >> 2;
        int ck = idx & 3;
        float v[8];
#pragma unroll
        for (int i = 0; i < 8; ++i) v[i] = src[(ck * 8 + i) * VOX + s];
        *reinterpret_cast<uint4*>(gT + (size_t)s * CH + ck * 8) =
            make_uint4(pack_h2(v[0], v[1]), pack_h2(v[2], v[3]),
                       pack_h2(v[4], v[5]), pack_h2(v[6], v[7]));
    }
    int pid = idx - VOX * 4;
    if (pid >= 0 && pid < 512) {        // pid = f*4 + qq
        int f  = pid >> 2;
        int qq = pid & 3;
        const float* wr = enc_w + f * CH + qq * 8;   // 8 contiguous k
        float4 a = *reinterpret_cast<const float4*>(wr);
        float4 b = *reinterpret_cast<const float4*>(wr + 4);
        // ewP[f*16 + qq*4 + i] = halves (k=qq*8+2i, qq*8+2i+1)
        *reinterpret_cast<uint4*>(ewP + (size_t)pid * 4) =
            make_uint4(pack_h2(a.x, a.y), pack_h2(a.z, a.w),
                       pack_h2(b.x, b.y), pack_h2(b.z, b.w));
    }
}

__device__ __forceinline__ void bspline_w(float t, float w[4]) {
    float t2 = t * t, t3 = t2 * t;
    const float k = 1.0f / 6.0f;
    w[0] = k * (1.0f - 3.0f * t + 3.0f * t2 - t3);
    w[1] = k * (4.0f - 6.0f * t2 + 3.0f * t3);
    w[2] = k * (1.0f + 3.0f * t + 3.0f * t2 - 3.0f * t3);
    w[3] = k * t3;
}

// f32 fma with f16 operand promoted in-instruction (exact same numerics as
// cvt_f32_f16 + fma_f32, but one VALU op instead of two).
__device__ __forceinline__ void fma_mix_lo(float& a, float w, uint32_t p) {
    asm("v_fma_mix_f32 %0, %1, %2, %0 op_sel:[0,0,0] op_sel_hi:[0,1,0]"
        : "+v"(a) : "v"(w), "v"(p));
}
__device__ __forceinline__ void fma_mix_hi(float& a, float w, uint32_t p) {
    asm("v_fma_mix_f32 %0, %1, %2, %0 op_sel:[0,1,0] op_sel_hi:[0,1,0]"
        : "+v"(a) : "v"(w), "v"(p));
}

// -------- Pass 2 ----------------------------------------------------------
// Phase 1: lane = eq(2b)|zsl(2b)|ck(2b); uint4 = 8 fp16 channels per load;
//   ALL 16 tap loads of a window issued into raw[16] (64 VGPRs) BEFORE any
//   consumption -> ~16 loads in flight per wave (was ~4 at VGPR=40; MLP is
//   the R2-measured binding constraint: FETCH dropped 52->30MB, time flat).
//   NOTE: launch_bounds min-waves relaxed 4 -> 3 (VGPR cap 128 -> 168); at
//   the 128 cap the raw[16]+asm-tied-acc allocation failed to build (R3).
// Phase 2: lane = feature pair, wave owns its own 16 elements (wave-private
//   LDS flow, no barrier). Weights in VGPRs; out stores NON-TEMPORAL so the
//   65 MB write stream doesn't evict gT (4.4 MB ~ L2-sized) from L2.
__global__ __launch_bounds__(256, 3) void lig_main(
    const float* __restrict__ nb, const __half* __restrict__ gT,
    const uint32_t* __restrict__ ewP, const float* __restrict__ enc_b,
    float* __restrict__ out, int batch) {

    __shared__ __align__(16) uint32_t xs[TILE * 16];   // 4 KB, h2 ch-pairs

    const int tid  = threadIdx.x;
    const int lane = tid & 63;
    const int wv   = tid >> 6;
    const int eq   = lane >> 4;         // element in quad
    const int zsl  = (lane >> 2) & 3;   // z tap
    const int ck   = (lane & 3) * 8;    // channel octet base
    const int base_e = blockIdx.x * TILE;
    (void)batch;

    // Hoist all nb loads (read-once stream -> non-temporal).
    float q0[4], q1[4], q2[4];
#pragma unroll
    for (int qi = 0; qi < 4; ++qi) {
        const int e = base_e + wv * 16 + qi * 4 + eq;
        q0[qi] = __builtin_nontemporal_load(nb + 3 * e);
        q1[qi] = __builtin_nontemporal_load(nb + 3 * e + 1);
        q2[qi] = __builtin_nontemporal_load(nb + 3 * e + 2);
    }

    // ---------------- Phase 1: interpolate 16 elements per wave ------------
#pragma unroll
    for (int qi = 0; qi < 4; ++qi) {
        const int eloc = wv * 16 + qi * 4 + eq;

        float ux = fminf(fmaxf(0.5f + 0.1f * q0[qi], 0.0f), 1.0f) * 40.0f;
        float uy = fminf(fmaxf(0.5f + 0.1f * q1[qi], 0.0f), 1.0f) * 40.0f;
        float uz = fminf(fmaxf(0.5f + 0.1f * q2[qi], 0.0f), 1.0f) * 40.0f;
        int bx = (int)ux, by = (int)uy, bz = (int)uz;
        float wx[4], wy[4], wz[4];
        bspline_w(ux - (float)bx, wx);
        bspline_w(uy - (float)by, wy);
        bspline_w(uz - (float)bz, wz);

        const float wzl = wz[zsl];      // fold z weight into x weights
#pragma unroll
        for (int o = 0; o < 4; ++o) wx[o] *= wzl;

        int X[4], Y[4];
#pragma unroll
        for (int o = 0; o < 4; ++o) {
            X[o] = min(max(bx + o - 1, 0), GN - 1) * (GN * GN * CH);
            Y[o] = min(max(by + o - 1, 0), GN - 1) * (GN * CH);
        }
        const int Zoff = min(max(bz + zsl - 1, 0), GN - 1) * CH + ck;

        // ---- issue ALL 16 gathers first (register-batched, MLP) ----
        uint4 raw[16];
#pragma unroll
        for (int i = 0; i < 4; ++i)
#pragma unroll
            for (int j = 0; j < 4; ++j)
                raw[i * 4 + j] =
                    *reinterpret_cast<const uint4*>(gT + (X[i] + Y[j] + Zoff));

        float acc[8];
#pragma unroll
        for (int k = 0; k < 8; ++k) acc[k] = 0.0f;

        // ---- consume ----
#pragma unroll
        for (int i = 0; i < 4; ++i) {
#pragma unroll
            for (int j = 0; j < 4; ++j) {
                const uint4 r = raw[i * 4 + j];
                const float wt = wx[i] * wy[j];
                fma_mix_lo(acc[0], wt, r.x);
                fma_mix_hi(acc[1], wt, r.x);
                fma_mix_lo(acc[2], wt, r.y);
                fma_mix_hi(acc[3], wt, r.y);
                fma_mix_lo(acc[4], wt, r.z);
                fma_mix_hi(acc[5], wt, r.z);
                fma_mix_lo(acc[6], wt, r.w);
                fma_mix_hi(acc[7], wt, r.w);
            }
        }

#pragma unroll
        for (int k = 0; k < 8; ++k) {
            acc[k] += __shfl_xor(acc[k], 4);
            acc[k] += __shfl_xor(acc[k], 8);
        }

        if ((lane & 12) == 0) {         // zsl==0 lanes hold the z-sums
            uint32_t d0 = __builtin_bit_cast(
                uint32_t, __builtin_amdgcn_cvt_pkrtz(acc[0], acc[1]));
            uint32_t d1 = __builtin_bit_cast(
                uint32_t, __builtin_amdgcn_cvt_pkrtz(acc[2], acc[3]));
            uint32_t d2 = __builtin_bit_cast(
                uint32_t, __builtin_amdgcn_cvt_pkrtz(acc[4], acc[5]));
            uint32_t d3 = __builtin_bit_cast(
                uint32_t, __builtin_amdgcn_cvt_pkrtz(acc[6], acc[7]));
            *reinterpret_cast<uint4*>(&xs[eloc * 16 + (lane & 3) * 4]) =
                make_uint4(d0, d1, d2, d3);
        }
    }

    // ---------------- Phase 2: 32 -> 128 matmul, coalesced nt stores -------
    const int f0 = lane * 2;
    uint32_t w0[16], w1[16];
    {
        const uint4* wp0 = reinterpret_cast<const uint4*>(ewP + (size_t)f0 * 16);
        const uint4* wp1 = reinterpret_cast<const uint4*>(ewP + (size_t)(f0 + 1) * 16);
#pragma unroll
        for (int g = 0; g < 4; ++g) {
            uint4 a = wp0[g];
            w0[4 * g + 0] = a.x; w0[4 * g + 1] = a.y;
            w0[4 * g + 2] = a.z; w0[4 * g + 3] = a.w;
            uint4 b = wp1[g];
            w1[4 * g + 0] = b.x; w1[4 * g + 1] = b.y;
            w1[4 * g + 2] = b.z; w1[4 * g + 3] = b.w;
        }
    }
    const float2 bb = *reinterpret_cast<const float2*>(enc_b + f0);

    float*          obase = out + (size_t)(base_e + wv * 16) * EF + f0;
    const uint32_t* xbase = xs + (size_t)(wv * 16) * 16;

#pragma unroll 4
    for (int i = 0; i < 16; ++i) {
        const uint32_t* xp = xbase + i * 16;
        uint4 x0 = *reinterpret_cast<const uint4*>(xp);       // broadcast
        uint4 x1 = *reinterpret_cast<const uint4*>(xp + 4);
        uint4 x2 = *reinterpret_cast<const uint4*>(xp + 8);
        uint4 x3 = *reinterpret_cast<const uint4*>(xp + 12);
        uint32_t xd[16] = {x0.x, x0.y, x0.z, x0.w, x1.x, x1.y, x1.z, x1.w,
                           x2.x, x2.y, x2.z, x2.w, x3.x, x3.y, x3.z, x3.w};
        float s0 = bb.x, s1 = bb.y;
#pragma unroll
        for (int p = 0; p < 16; ++p) {
            s0 = __builtin_amdgcn_fdot2(__builtin_bit_cast(h2, xd[p]),
                                        __builtin_bit_cast(h2, w0[p]), s0, false);
            s1 = __builtin_amdgcn_fdot2(__builtin_bit_cast(h2, xd[p]),
                                        __builtin_bit_cast(h2, w1[p]), s1, false);
        }
        f2v o; o.x = s0; o.y = s1;
        __builtin_nontemporal_store(
            o, reinterpret_cast<f2v*>(obase + (size_t)i * EF));
    }
}

extern "C" void kernel_launch(void* const* d_in, const int* in_sizes, int n_in,
                              void* d_out, int out_size, void* d_ws,
                              size_t ws_size, hipStream_t stream) {
    const float* nb   = (const float*)d_in[0];
    const float* grid = (const float*)d_in[1];
    const float* ew   = (const float*)d_in[2];
    const float* eb   = (const float*)d_in[3];
    float*       out  = (float*)d_out;
    __half*      gTh  = (__half*)d_ws;                       // 4.41 MB
    uint32_t*    ewP  = (uint32_t*)(gTh + (size_t)VOX * CH); // + 8 KB

    int batch = in_sizes[0] / 3;

    int prep_blocks = (VOX * 4 + 512 + 255) / 256;
    prep_k<<<prep_blocks, 256, 0, stream>>>(grid, ew, gTh, ewP);
    lig_main<<<batch / TILE, 256, 0, stream>>>(nb, gTh, ewP, eb, out, batch);
}

// Round 5
// 121.537 us; speedup vs baseline: 1.0352x; 1.0225x over previous
//
#include <hip/hip_runtime.h>
#include <hip/hip_fp16.h>
#include <cstdint>

constexpr int GN   = 41;                // grid points per dim
constexpr int VOX  = GN * GN * GN;      // 68921 spatial points
constexpr int CH   = 32;                // channels
constexpr int EF   = 128;               // encoder features
constexpr int TILE = 64;                // elements per block

typedef _Float16 h2 __attribute__((ext_vector_type(2)));
typedef float    f2v __attribute__((ext_vector_type(2)));

__device__ __forceinline__ uint32_t pack_h2(float a, float b) {
    __half2 h = __floats2half2_rn(a, b);
    return __builtin_bit_cast(uint32_t, h);
}

// -------- Pass 1: grid [C][X][Y][Z] fp32 -> [X][Y][Z][C] fp16 (gT)  +  ----
// -------- enc_w fp32 -> packed f16 k-pairs (ewP[f][p], p = k/2) ------------
__global__ __launch_bounds__(256) void prep_k(
    const float* __restrict__ src, const float* __restrict__ enc_w,
    __half* __restrict__ gT, uint32_t* __restrict__ ewP) {
    int idx = blockIdx.x * 256 + threadIdx.x;
    if (idx < VOX * 4) {
        int s  = idx >> 2;
        int ck = idx & 3;
        float v[8];
#pragma unroll
        for (int i = 0; i < 8; ++i) v[i] = src[(ck * 8 + i) * VOX + s];
        *reinterpret_cast<uint4*>(gT + (size_t)s * CH + ck * 8) =
            make_uint4(pack_h2(v[0], v[1]), pack_h2(v[2], v[3]),
                       pack_h2(v[4], v[5]), pack_h2(v[6], v[7]));
    }
    int pid = idx - VOX * 4;
    if (pid >= 0 && pid < 512) {        // pid = f*4 + qq
        int f  = pid >> 2;
        int qq = pid & 3;
        const float* wr = enc_w + f * CH + qq * 8;   // 8 contiguous k
        float4 a = *reinterpret_cast<const float4*>(wr);
        float4 b = *reinterpret_cast<const float4*>(wr + 4);
        // ewP[f*16 + qq*4 + i] = halves (k=qq*8+2i, qq*8+2i+1)
        *reinterpret_cast<uint4*>(ewP + (size_t)pid * 4) =
            make_uint4(pack_h2(a.x, a.y), pack_h2(a.z, a.w),
                       pack_h2(b.x, b.y), pack_h2(b.z, b.w));
    }
}

__device__ __forceinline__ void bspline_w(float t, float w[4]) {
    float t2 = t * t, t3 = t2 * t;
    const float k = 1.0f / 6.0f;
    w[0] = k * (1.0f - 3.0f * t + 3.0f * t2 - t3);
    w[1] = k * (4.0f - 6.0f * t2 + 3.0f * t3);
    w[2] = k * (1.0f + 3.0f * t + 3.0f * t2 - 3.0f * t3);
    w[3] = k * t3;
}

// f32 fma with f16 operand promoted in-instruction (exact same numerics as
// cvt_f32_f16 + fma_f32, but one VALU op instead of two).
__device__ __forceinline__ void fma_mix_lo(float& a, float w, uint32_t p) {
    asm("v_fma_mix_f32 %0, %1, %2, %0 op_sel:[0,0,0] op_sel_hi:[0,1,0]"
        : "+v"(a) : "v"(w), "v"(p));
}
__device__ __forceinline__ void fma_mix_hi(float& a, float w, uint32_t p) {
    asm("v_fma_mix_f32 %0, %1, %2, %0 op_sel:[0,1,0] op_sel_hi:[0,1,0]"
        : "+v"(a) : "v"(w), "v"(p));
}

// -------- Pass 2 ----------------------------------------------------------
// Phase 1: lane = eq(2b)|zsl(2b)|ck(2b); uint4 = 8 fp16 channels per load.
//   ALL 16 tap loads issued into raw[16], then sched_barrier(0) PINS them
//   above the consume loop (R4 showed the compiler otherwise re-sinks each
//   load to its use: VGPR stayed 40 and the batch had no codegen effect).
//   ~16 loads in flight per wave vs ~4. v_fma_mix f32 accumulate; z-reduce
//   shfl_xor(4,8); lig_x -> LDS packed h2.
// Phase 2: lane = feature pair, wave owns its own 16 elements (wave-private
//   LDS flow, no barrier). Weights in VGPRs; out stores NON-TEMPORAL so the
//   65 MB write stream doesn't evict gT (4.4 MB ~ L2-sized) from L2.
__global__ __launch_bounds__(256, 3) void lig_main(
    const float* __restrict__ nb, const __half* __restrict__ gT,
    const uint32_t* __restrict__ ewP, const float* __restrict__ enc_b,
    float* __restrict__ out, int batch) {

    __shared__ __align__(16) uint32_t xs[TILE * 16];   // 4 KB, h2 ch-pairs

    const int tid  = threadIdx.x;
    const int lane = tid & 63;
    const int wv   = tid >> 6;
    const int eq   = lane >> 4;         // element in quad
    const int zsl  = (lane >> 2) & 3;   // z tap
    const int ck   = (lane & 3) * 8;    // channel octet base
    const int base_e = blockIdx.x * TILE;
    (void)batch;

    // Hoist all nb loads (read-once stream -> non-temporal).
    float q0[4], q1[4], q2[4];
#pragma unroll
    for (int qi = 0; qi < 4; ++qi) {
        const int e = base_e + wv * 16 + qi * 4 + eq;
        q0[qi] = __builtin_nontemporal_load(nb + 3 * e);
        q1[qi] = __builtin_nontemporal_load(nb + 3 * e + 1);
        q2[qi] = __builtin_nontemporal_load(nb + 3 * e + 2);
    }

    // ---------------- Phase 1: interpolate 16 elements per wave ------------
#pragma unroll
    for (int qi = 0; qi < 4; ++qi) {
        const int eloc = wv * 16 + qi * 4 + eq;

        float ux = fminf(fmaxf(0.5f + 0.1f * q0[qi], 0.0f), 1.0f) * 40.0f;
        float uy = fminf(fmaxf(0.5f + 0.1f * q1[qi], 0.0f), 1.0f) * 40.0f;
        float uz = fminf(fmaxf(0.5f + 0.1f * q2[qi], 0.0f), 1.0f) * 40.0f;
        int bx = (int)ux, by = (int)uy, bz = (int)uz;
        float wx[4], wy[4], wz[4];
        bspline_w(ux - (float)bx, wx);
        bspline_w(uy - (float)by, wy);
        bspline_w(uz - (float)bz, wz);

        const float wzl = wz[zsl];      // fold z weight into x weights
#pragma unroll
        for (int o = 0; o < 4; ++o) wx[o] *= wzl;

        int X[4], Y[4];
#pragma unroll
        for (int o = 0; o < 4; ++o) {
            X[o] = min(max(bx + o - 1, 0), GN - 1) * (GN * GN * CH);
            Y[o] = min(max(by + o - 1, 0), GN - 1) * (GN * CH);
        }
        const int Zoff = min(max(bz + zsl - 1, 0), GN - 1) * CH + ck;

        // ---- issue ALL 16 gathers first (register-batched, MLP) ----
        uint4 raw[16];
#pragma unroll
        for (int i = 0; i < 4; ++i)
#pragma unroll
            for (int j = 0; j < 4; ++j)
                raw[i * 4 + j] =
                    *reinterpret_cast<const uint4*>(gT + (X[i] + Y[j] + Zoff));

        // Pin the 16 loads above the consumers (compiler otherwise re-sinks
        // them to their uses and MLP collapses back to ~4 — R4 evidence).
        __builtin_amdgcn_sched_barrier(0);

        float acc[8];
#pragma unroll
        for (int k = 0; k < 8; ++k) acc[k] = 0.0f;

        // ---- consume ----
#pragma unroll
        for (int i = 0; i < 4; ++i) {
#pragma unroll
            for (int j = 0; j < 4; ++j) {
                const uint4 r = raw[i * 4 + j];
                const float wt = wx[i] * wy[j];
                fma_mix_lo(acc[0], wt, r.x);
                fma_mix_hi(acc[1], wt, r.x);
                fma_mix_lo(acc[2], wt, r.y);
                fma_mix_hi(acc[3], wt, r.y);
                fma_mix_lo(acc[4], wt, r.z);
                fma_mix_hi(acc[5], wt, r.z);
                fma_mix_lo(acc[6], wt, r.w);
                fma_mix_hi(acc[7], wt, r.w);
            }
        }

#pragma unroll
        for (int k = 0; k < 8; ++k) {
            acc[k] += __shfl_xor(acc[k], 4);
            acc[k] += __shfl_xor(acc[k], 8);
        }

        if ((lane & 12) == 0) {         // zsl==0 lanes hold the z-sums
            uint32_t d0 = __builtin_bit_cast(
                uint32_t, __builtin_amdgcn_cvt_pkrtz(acc[0], acc[1]));
            uint32_t d1 = __builtin_bit_cast(
                uint32_t, __builtin_amdgcn_cvt_pkrtz(acc[2], acc[3]));
            uint32_t d2 = __builtin_bit_cast(
                uint32_t, __builtin_amdgcn_cvt_pkrtz(acc[4], acc[5]));
            uint32_t d3 = __builtin_bit_cast(
                uint32_t, __builtin_amdgcn_cvt_pkrtz(acc[6], acc[7]));
            *reinterpret_cast<uint4*>(&xs[eloc * 16 + (lane & 3) * 4]) =
                make_uint4(d0, d1, d2, d3);
        }
    }

    // ---------------- Phase 2: 32 -> 128 matmul, coalesced nt stores -------
    const int f0 = lane * 2;
    uint32_t w0[16], w1[16];
    {
        const uint4* wp0 = reinterpret_cast<const uint4*>(ewP + (size_t)f0 * 16);
        const uint4* wp1 = reinterpret_cast<const uint4*>(ewP + (size_t)(f0 + 1) * 16);
#pragma unroll
        for (int g = 0; g < 4; ++g) {
            uint4 a = wp0[g];
            w0[4 * g + 0] = a.x; w0[4 * g + 1] = a.y;
            w0[4 * g + 2] = a.z; w0[4 * g + 3] = a.w;
            uint4 b = wp1[g];
            w1[4 * g + 0] = b.x; w1[4 * g + 1] = b.y;
            w1[4 * g + 2] = b.z; w1[4 * g + 3] = b.w;
        }
    }
    const float2 bb = *reinterpret_cast<const float2*>(enc_b + f0);

    float*          obase = out + (size_t)(base_e + wv * 16) * EF + f0;
    const uint32_t* xbase = xs + (size_t)(wv * 16) * 16;

#pragma unroll 4
    for (int i = 0; i < 16; ++i) {
        const uint32_t* xp = xbase + i * 16;
        uint4 x0 = *reinterpret_cast<const uint4*>(xp);       // broadcast
        uint4 x1 = *reinterpret_cast<const uint4*>(xp + 4);
        uint4 x2 = *reinterpret_cast<const uint4*>(xp + 8);
        uint4 x3 = *reinterpret_cast<const uint4*>(xp + 12);
        uint32_t xd[16] = {x0.x, x0.y, x0.z, x0.w, x1.x, x1.y, x1.z, x1.w,
                           x2.x, x2.y, x2.z, x2.w, x3.x, x3.y, x3.z, x3.w};
        float s0 = bb.x, s1 = bb.y;
#pragma unroll
        for (int p = 0; p < 16; ++p) {
            s0 = __builtin_amdgcn_fdot2(__builtin_bit_cast(h2, xd[p]),
                                        __builtin_bit_cast(h2, w0[p]), s0, false);
            s1 = __builtin_amdgcn_fdot2(__builtin_bit_cast(h2, xd[p]),
                                        __builtin_bit_cast(h2, w1[p]), s1, false);
        }
        f2v o; o.x = s0; o.y = s1;
        __builtin_nontemporal_store(
            o, reinterpret_cast<f2v*>(obase + (size_t)i * EF));
    }
}

extern "C" void kernel_launch(void* const* d_in, const int* in_sizes, int n_in,
                              void* d_out, int out_size, void* d_ws,
                              size_t ws_size, hipStream_t stream) {
    const float* nb   = (const float*)d_in[0];
    const float* grid = (const float*)d_in[1];
    const float* ew   = (const float*)d_in[2];
    const float* eb   = (const float*)d_in[3];
    float*       out  = (float*)d_out;
    __half*      gTh  = (__half*)d_ws;                       // 4.41 MB
    uint32_t*    ewP  = (uint32_t*)(gTh + (size_t)VOX * CH); // + 8 KB

    int batch = in_sizes[0] / 3;

    int prep_blocks = (VOX * 4 + 512 + 255) / 256;
    prep_k<<<prep_blocks, 256, 0, stream>>>(grid, ew, gTh, ewP);
    lig_main<<<batch / TILE, 256, 0, stream>>>(nb, gTh, ewP, eb, out, batch);
}

// Round 6
// 118.902 us; speedup vs baseline: 1.0582x; 1.0222x over previous
//
#include <hip/hip_runtime.h>
#include <hip/hip_fp16.h>
#include <cstdint>

constexpr int GN   = 41;                // grid points per dim
constexpr int VOX  = GN * GN * GN;      // 68921 spatial points
constexpr int CH   = 32;                // channels
constexpr int EF   = 128;               // encoder features
constexpr int TILE = 64;                // elements per block

typedef _Float16 h2 __attribute__((ext_vector_type(2)));
typedef _Float16 h8 __attribute__((ext_vector_type(8)));
typedef float    f4 __attribute__((ext_vector_type(4)));

__device__ __forceinline__ uint32_t pack_h2(float a, float b) {
    __half2 h = __floats2half2_rn(a, b);
    return __builtin_bit_cast(uint32_t, h);
}

// -------- Pass 1: grid [C][X][Y][Z] fp32 -> [X][Y][Z][C] fp16 (gT)  +  ----
// -------- enc_w fp32 -> MFMA B-fragments (8 n-tiles of 16x16x32_f16) ------
// ewB[nt*64 + l] (uint4 = 8 f16): B[k][n] with n = nt*16 + (l&15),
//   k = (l>>4)*8 + j  (j = 0..7, h2 pairs in k-order).
__global__ __launch_bounds__(256) void prep_k(
    const float* __restrict__ src, const float* __restrict__ enc_w,
    __half* __restrict__ gT, uint32_t* __restrict__ ewB) {
    int idx = blockIdx.x * 256 + threadIdx.x;
    if (idx < VOX * 4) {
        int s  = idx >> 2;
        int ck = idx & 3;
        float v[8];
#pragma unroll
        for (int i = 0; i < 8; ++i) v[i] = src[(ck * 8 + i) * VOX + s];
        *reinterpret_cast<uint4*>(gT + (size_t)s * CH + ck * 8) =
            make_uint4(pack_h2(v[0], v[1]), pack_h2(v[2], v[3]),
                       pack_h2(v[4], v[5]), pack_h2(v[6], v[7]));
    }
    int pid = idx - VOX * 4;
    if (pid >= 0 && pid < 512) {        // pid = nt*64 + l
        int nt = pid >> 6;
        int l  = pid & 63;
        int f  = nt * 16 + (l & 15);
        int k0 = (l >> 4) * 8;
        const float* wr = enc_w + f * CH + k0;       // 8 contiguous k
        float4 a = *reinterpret_cast<const float4*>(wr);
        float4 b = *reinterpret_cast<const float4*>(wr + 4);
        *reinterpret_cast<uint4*>(ewB + (size_t)pid * 4) =
            make_uint4(pack_h2(a.x, a.y), pack_h2(a.z, a.w),
                       pack_h2(b.x, b.y), pack_h2(b.z, b.w));
    }
}

__device__ __forceinline__ void bspline_w(float t, float w[4]) {
    float t2 = t * t, t3 = t2 * t;
    const float k = 1.0f / 6.0f;
    w[0] = k * (1.0f - 3.0f * t + 3.0f * t2 - t3);
    w[1] = k * (4.0f - 6.0f * t2 + 3.0f * t3);
    w[2] = k * (1.0f + 3.0f * t + 3.0f * t2 - 3.0f * t3);
    w[3] = k * t3;
}

// f32 fma with f16 operand promoted in-instruction (exact same numerics as
// cvt_f32_f16 + fma_f32, but one VALU op instead of two).
__device__ __forceinline__ void fma_mix_lo(float& a, float w, uint32_t p) {
    asm("v_fma_mix_f32 %0, %1, %2, %0 op_sel:[0,0,0] op_sel_hi:[0,1,0]"
        : "+v"(a) : "v"(w), "v"(p));
}
__device__ __forceinline__ void fma_mix_hi(float& a, float w, uint32_t p) {
    asm("v_fma_mix_f32 %0, %1, %2, %0 op_sel:[0,1,0] op_sel_hi:[0,1,0]"
        : "+v"(a) : "v"(w), "v"(p));
}

// -------- Pass 2 ----------------------------------------------------------
// Phase 1 (R5-verified): lane = eq(2b)|zsl(2b)|ck(2b); all 16 tap loads
//   batched into raw[16] + sched_barrier(0) pin (R4: compiler re-sinks
//   otherwise); v_fma_mix accumulate; z-reduce shfl_xor(4,8); lig_x -> LDS
//   packed h2 (dword = ch-pair, k-order -> IS the MFMA A-frag layout).
// Phase 2 (NEW): per-wave 16x128x32 matmul = 8 x v_mfma_f32_16x16x32_f16
//   (replaces 512 v_dot2 VALU instrs ~1024 cyc with ~40 cyc matrix pipe).
//   A-frag: one ds_read_b128 (lane l -> elem l&15, ch (l>>4)*8..+7).
//   B-frags prepacked by prep_k (8 x 16 B loads, L1-resident).
//   C-in = bias broadcast (D col = lane&15 = feature, m89-verified layout).
//   Wave-private LDS flow, no barrier. Stores nontemporal (R1: protects gT
//   L2 residency; FETCH 52->30 MB).
__global__ __launch_bounds__(256, 3) void lig_main(
    const float* __restrict__ nb, const __half* __restrict__ gT,
    const uint32_t* __restrict__ ewB, const float* __restrict__ enc_b,
    float* __restrict__ out, int batch) {

    __shared__ __align__(16) uint32_t xs[TILE * 16];   // 4 KB, h2 ch-pairs

    const int tid  = threadIdx.x;
    const int lane = tid & 63;
    const int wv   = tid >> 6;
    const int eq   = lane >> 4;         // element in quad
    const int zsl  = (lane >> 2) & 3;   // z tap
    const int ck   = (lane & 3) * 8;    // channel octet base
    const int base_e = blockIdx.x * TILE;
    (void)batch;

    // Hoist all nb loads (read-once stream -> non-temporal).
    float q0[4], q1[4], q2[4];
#pragma unroll
    for (int qi = 0; qi < 4; ++qi) {
        const int e = base_e + wv * 16 + qi * 4 + eq;
        q0[qi] = __builtin_nontemporal_load(nb + 3 * e);
        q1[qi] = __builtin_nontemporal_load(nb + 3 * e + 1);
        q2[qi] = __builtin_nontemporal_load(nb + 3 * e + 2);
    }

    // ---------------- Phase 1: interpolate 16 elements per wave ------------
#pragma unroll
    for (int qi = 0; qi < 4; ++qi) {
        const int eloc = wv * 16 + qi * 4 + eq;

        float ux = fminf(fmaxf(0.5f + 0.1f * q0[qi], 0.0f), 1.0f) * 40.0f;
        float uy = fminf(fmaxf(0.5f + 0.1f * q1[qi], 0.0f), 1.0f) * 40.0f;
        float uz = fminf(fmaxf(0.5f + 0.1f * q2[qi], 0.0f), 1.0f) * 40.0f;
        int bx = (int)ux, by = (int)uy, bz = (int)uz;
        float wx[4], wy[4], wz[4];
        bspline_w(ux - (float)bx, wx);
        bspline_w(uy - (float)by, wy);
        bspline_w(uz - (float)bz, wz);

        const float wzl = wz[zsl];      // fold z weight into x weights
#pragma unroll
        for (int o = 0; o < 4; ++o) wx[o] *= wzl;

        int X[4], Y[4];
#pragma unroll
        for (int o = 0; o < 4; ++o) {
            X[o] = min(max(bx + o - 1, 0), GN - 1) * (GN * GN * CH);
            Y[o] = min(max(by + o - 1, 0), GN - 1) * (GN * CH);
        }
        const int Zoff = min(max(bz + zsl - 1, 0), GN - 1) * CH + ck;

        // ---- issue ALL 16 gathers first (register-batched, MLP) ----
        uint4 raw[16];
#pragma unroll
        for (int i = 0; i < 4; ++i)
#pragma unroll
            for (int j = 0; j < 4; ++j)
                raw[i * 4 + j] =
                    *reinterpret_cast<const uint4*>(gT + (X[i] + Y[j] + Zoff));

        // Pin the 16 loads above the consumers (compiler otherwise re-sinks
        // them to their uses and MLP collapses back to ~4 — R4 evidence).
        __builtin_amdgcn_sched_barrier(0);

        float acc[8];
#pragma unroll
        for (int k = 0; k < 8; ++k) acc[k] = 0.0f;

        // ---- consume ----
#pragma unroll
        for (int i = 0; i < 4; ++i) {
#pragma unroll
            for (int j = 0; j < 4; ++j) {
                const uint4 r = raw[i * 4 + j];
                const float wt = wx[i] * wy[j];
                fma_mix_lo(acc[0], wt, r.x);
                fma_mix_hi(acc[1], wt, r.x);
                fma_mix_lo(acc[2], wt, r.y);
                fma_mix_hi(acc[3], wt, r.y);
                fma_mix_lo(acc[4], wt, r.z);
                fma_mix_hi(acc[5], wt, r.z);
                fma_mix_lo(acc[6], wt, r.w);
                fma_mix_hi(acc[7], wt, r.w);
            }
        }

#pragma unroll
        for (int k = 0; k < 8; ++k) {
            acc[k] += __shfl_xor(acc[k], 4);
            acc[k] += __shfl_xor(acc[k], 8);
        }

        if ((lane & 12) == 0) {         // zsl==0 lanes hold the z-sums
            uint32_t d0 = __builtin_bit_cast(
                uint32_t, __builtin_amdgcn_cvt_pkrtz(acc[0], acc[1]));
            uint32_t d1 = __builtin_bit_cast(
                uint32_t, __builtin_amdgcn_cvt_pkrtz(acc[2], acc[3]));
            uint32_t d2 = __builtin_bit_cast(
                uint32_t, __builtin_amdgcn_cvt_pkrtz(acc[4], acc[5]));
            uint32_t d3 = __builtin_bit_cast(
                uint32_t, __builtin_amdgcn_cvt_pkrtz(acc[6], acc[7]));
            *reinterpret_cast<uint4*>(&xs[eloc * 16 + (lane & 3) * 4]) =
                make_uint4(d0, d1, d2, d3);
        }
    }

    // ---------------- Phase 2: 16x128x32 matmul via MFMA -------------------
    const int col = lane & 15;          // A row (element) / B,D col (feature)
    const int kg  = lane >> 4;          // k-group (8 channels)

    // A fragment: wave-private element col, channels kg*8..kg*8+7.
    const h8 af = *reinterpret_cast<const h8*>(
        &xs[(wv * 16 + col) * 16 + kg * 4]);

    float* ob = out + (size_t)(base_e + wv * 16 + kg * 4) * EF + col;

#pragma unroll
    for (int nt = 0; nt < 8; ++nt) {
        const h8 bf = *reinterpret_cast<const h8*>(
            ewB + ((size_t)nt * 64 + lane) * 4);
        const float bias = enc_b[nt * 16 + col];
        f4 acc = {bias, bias, bias, bias};
        acc = __builtin_amdgcn_mfma_f32_16x16x32_f16(af, bf, acc, 0, 0, 0);
#pragma unroll
        for (int r = 0; r < 4; ++r)     // D: elem kg*4+r, feature nt*16+col
            __builtin_nontemporal_store(acc[r],
                                        ob + (size_t)r * EF + nt * 16);
    }
}

extern "C" void kernel_launch(void* const* d_in, const int* in_sizes, int n_in,
                              void* d_out, int out_size, void* d_ws,
                              size_t ws_size, hipStream_t stream) {
    const float* nb   = (const float*)d_in[0];
    const float* grid = (const float*)d_in[1];
    const float* ew   = (const float*)d_in[2];
    const float* eb   = (const float*)d_in[3];
    float*       out  = (float*)d_out;
    __half*      gTh  = (__half*)d_ws;                       // 4.41 MB
    uint32_t*    ewB  = (uint32_t*)(gTh + (size_t)VOX * CH); // + 8 KB

    int batch = in_sizes[0] / 3;

    int prep_blocks = (VOX * 4 + 512 + 255) / 256;
    prep_k<<<prep_blocks, 256, 0, stream>>>(grid, ew, gTh, ewB);
    lig_main<<<batch / TILE, 256, 0, stream>>>(nb, gTh, ewB, eb, out, batch);
}